// Round 1
// baseline (39986.316 us; speedup 1.0000x reference)
//
#include <hip/hip_runtime.h>
#include <hip/hip_cooperative_groups.h>
#include <math.h>

namespace cg = cooperative_groups;

// Problem constants (from reference): SEQ_LEN=512, BATCH=64, INPUT=256, HIDDEN=512
#define TT 512
#define BB 64
#define II 256
#define HH 512

// Tiling: block owns 32 batch rows x 4 hidden units x 4 gates = 512 dots, 1/thread.
#define BTILE 32
#define HTILE 4
#define NCOLS 16            // 4 gates * HTILE
#define NTHREADS 512
#define NBLOCKS 256         // (64/BTILE) * (512/HTILE) = 2 * 128

// LDS row strides padded (+4 floats) to spread the 16-distinct-row wave read
// across banks: (516 mod 32)=4 -> rows c and c+8 share banks (2-way, free).
#define WH_STRIDE 516
#define WX_STRIDE 260

__device__ __forceinline__ float sigmoidf_(float v) {
    return 1.0f / (1.0f + __expf(-v));
}

__global__ void __launch_bounds__(NTHREADS, 1)
lstm_persistent(const float* __restrict__ x,
                const float* __restrict__ Wx,
                const float* __restrict__ bx,
                const float* __restrict__ Wh,
                const float* __restrict__ bh,
                float* __restrict__ out)
{
    __shared__ float WhL[NCOLS * WH_STRIDE];   // 33,024 B
    __shared__ float WxL[NCOLS * WX_STRIDE];   // 16,640 B
    __shared__ float preL[BTILE * NCOLS];      //  2,048 B   total ~50.7 KB

    cg::grid_group grid = cg::this_grid();

    const int blk   = blockIdx.x;
    const int b0    = (blk & 1) * BTILE;     // 2 batch tiles
    const int hbase = (blk >> 1) * HTILE;    // 128 hidden tiles

    const int tid = threadIdx.x;
    const int bl  = tid >> 4;   // 0..31  batch row within tile
    const int c   = tid & 15;   // 0..15  column = g*HTILE + hl
    const int g   = c >> 2;     // gate 0..3 (f,i,o,c)
    const int hl  = c & 3;

    const int unit = g * HH + hbase + hl;    // row index into Wx/Wh/bx/bh

    // ---- Stage weights into LDS once (coalesced float4) ----
    {
        const int nf4h = NCOLS * (HH / 4);   // 2048 float4
        for (int idx = tid; idx < nf4h; idx += NTHREADS) {
            int row = idx >> 7;              // /128
            int pos = idx & 127;
            int gg = row >> 2, hh = row & 3;
            float4 v = ((const float4*)(Wh + (size_t)(gg * HH + hbase + hh) * HH))[pos];
            *((float4*)&WhL[row * WH_STRIDE + pos * 4]) = v;
        }
        const int nf4x = NCOLS * (II / 4);   // 1024 float4
        for (int idx = tid; idx < nf4x; idx += NTHREADS) {
            int row = idx >> 6;              // /64
            int pos = idx & 63;
            int gg = row >> 2, hh = row & 3;
            float4 v = ((const float4*)(Wx + (size_t)(gg * HH + hbase + hh) * II))[pos];
            *((float4*)&WxL[row * WX_STRIDE + pos * 4]) = v;
        }
    }
    const float bias = bx[unit] + bh[unit];
    float c_state = 0.0f;                    // valid for tid < BTILE*HTILE
    __syncthreads();

    const size_t HSEQ = (size_t)TT * BB * HH;

    for (int t = 0; t < TT; ++t) {
        float acc = bias;

        // x-projection: dot(x[t][b][:], Wx[g][h][:])  (K=256)
        {
            const float4* xr = (const float4*)(x + ((size_t)t * BB + (b0 + bl)) * II);
            const float4* wr = (const float4*)&WxL[c * WX_STRIDE];
            #pragma unroll 8
            for (int i = 0; i < II / 4; ++i) {
                float4 a = xr[i];
                float4 w = wr[i];
                acc = fmaf(a.x, w.x, acc);
                acc = fmaf(a.y, w.y, acc);
                acc = fmaf(a.z, w.z, acc);
                acc = fmaf(a.w, w.w, acc);
            }
        }
        // recurrent projection: dot(h[t-1][b][:], Wh[g][h][:])  (K=512); h0 = 0
        if (t > 0) {
            const float4* hr = (const float4*)(out + ((size_t)(t - 1) * BB + (b0 + bl)) * HH);
            const float4* wr = (const float4*)&WhL[c * WH_STRIDE];
            #pragma unroll 8
            for (int j = 0; j < HH / 4; ++j) {
                float4 a = hr[j];
                float4 w = wr[j];
                acc = fmaf(a.x, w.x, acc);
                acc = fmaf(a.y, w.y, acc);
                acc = fmaf(a.z, w.z, acc);
                acc = fmaf(a.w, w.w, acc);
            }
        }
        preL[bl * NCOLS + c] = acc;
        __syncthreads();

        // Gate combine: 128 threads, one (b,h) pair each; c_state lives in-register.
        if (tid < BTILE * HTILE) {
            const int b2 = tid >> 2;     // 0..31
            const int h2 = tid & 3;      // 0..3
            const float* p = &preL[b2 * NCOLS];
            float fg = sigmoidf_(p[0 * HTILE + h2]);
            float ig = sigmoidf_(p[1 * HTILE + h2]);
            float og = sigmoidf_(p[2 * HTILE + h2]);
            float cg_ = tanhf(p[3 * HTILE + h2]);
            float cn = fg * c_state + ig * cg_;
            float hv = og * tanhf(cn);
            c_state = cn;
            size_t oidx = ((size_t)t * BB + (b0 + b2)) * HH + hbase + h2;
            out[oidx] = hv;
            if (t == TT - 1) {
                size_t r = (size_t)(b0 + b2) * HH + hbase + h2;
                out[HSEQ + r] = hv;                       // h_last
                out[HSEQ + (size_t)BB * HH + r] = cn;     // c_last
            }
        }

        // Publish h_t device-wide, then barrier before anyone reads it at t+1.
        __threadfence();
        grid.sync();
    }
}

extern "C" void kernel_launch(void* const* d_in, const int* in_sizes, int n_in,
                              void* d_out, int out_size, void* d_ws, size_t ws_size,
                              hipStream_t stream)
{
    const float* x  = (const float*)d_in[0];
    const float* Wx = (const float*)d_in[1];
    const float* bx = (const float*)d_in[2];
    const float* Wh = (const float*)d_in[3];
    const float* bh = (const float*)d_in[4];
    float* out = (float*)d_out;

    void* args[] = { (void*)&x, (void*)&Wx, (void*)&bx, (void*)&Wh, (void*)&bh, (void*)&out };
    hipLaunchCooperativeKernel((const void*)lstm_persistent,
                               dim3(NBLOCKS), dim3(NTHREADS),
                               args, 0, stream);
}

// Round 2
// 11884.091 us; speedup vs baseline: 3.3647x; 3.3647x over previous
//
#include <hip/hip_runtime.h>
#include <hip/hip_cooperative_groups.h>
#include <math.h>

namespace cg = cooperative_groups;

// Problem constants: SEQ_LEN=512, BATCH=64, INPUT=256, HIDDEN=512
#define TT 512
#define BB 64
#define II 256
#define HH 512

// Tiling: block owns 32 batch rows x (4 hidden units x 4 gates) = 512 dots, 1/thread.
#define BTILE 32
#define HTILE 4
#define NCOLS 16            // 4 gates * HTILE
#define NTHREADS 512
#define NBLOCKS 256         // (64/BTILE) * (512/HTILE)

// LDS row strides padded (+4 floats): 2-way bank aliasing only (free per m136).
#define WH_STRIDE 516
#define WX_STRIDE 260

__device__ __forceinline__ float sigmoidf_(float v) {
    return 1.0f / (1.0f + __expf(-v));
}

__global__ void __launch_bounds__(NTHREADS, 1)
lstm_persistent(const float* __restrict__ x,
                const float* __restrict__ Wx,
                const float* __restrict__ bx,
                const float* __restrict__ Wh,
                const float* __restrict__ bh,
                float* __restrict__ out,
                unsigned int* __restrict__ cnt,   // [TT] barrier counters (in d_ws)
                float* __restrict__ hbuf)         // [2][BB*HH] h ping-pong (in d_ws)
{
    __shared__ float WhL[NCOLS * WH_STRIDE];   // 33,024 B
    __shared__ float WxL[NCOLS * WX_STRIDE];   // 16,640 B
    __shared__ float preL[BTILE * NCOLS];      //  2,048 B

    cg::grid_group grid = cg::this_grid();

    const int blk   = blockIdx.x;
    const int b0    = (blk & 1) * BTILE;
    const int hbase = (blk >> 1) * HTILE;

    const int tid = threadIdx.x;
    const int bl  = tid >> 4;   // 0..31 batch row in tile
    const int c   = tid & 15;   // 0..15 column = g*HTILE + hl
    const int g   = c >> 2;
    const int hl  = c & 3;
    const int unit = g * HH + hbase + hl;

    // ---- Stage weights into LDS (plain cached loads, once) ----
    {
        const int nf4h = NCOLS * (HH / 4);
        for (int idx = tid; idx < nf4h; idx += NTHREADS) {
            int row = idx >> 7, pos = idx & 127;
            int gg = row >> 2, hh = row & 3;
            float4 v = ((const float4*)(Wh + (size_t)(gg * HH + hbase + hh) * HH))[pos];
            *((float4*)&WhL[row * WH_STRIDE + pos * 4]) = v;
        }
        const int nf4x = NCOLS * (II / 4);
        for (int idx = tid; idx < nf4x; idx += NTHREADS) {
            int row = idx >> 6, pos = idx & 63;
            int gg = row >> 2, hh = row & 3;
            float4 v = ((const float4*)(Wx + (size_t)(gg * HH + hbase + hh) * II))[pos];
            *((float4*)&WxL[row * WX_STRIDE + pos * 4]) = v;
        }
    }
    const float bias = bx[unit] + bh[unit];
    float c_state = 0.0f;

    // ---- Init phase: zero barrier counters + h_{-1} buffer, then ONE grid sync ----
    {
        int idx = blk * NTHREADS + tid;
        if (idx < TT) cnt[idx] = 0u;
        if (idx < BB * HH) hbuf[idx] = 0.0f;   // buf[0] = h_{-1} = 0
    }
    grid.sync();   // the only full cooperative sync; publishes the zeroed ws

    const size_t HSEQ = (size_t)TT * BB * HH;

    for (int t = 0; t < TT; ++t) {
        const float* hprev = hbuf + (size_t)(t & 1) * (BB * HH);        // h_{t-1}
        float*       hnext = hbuf + (size_t)((t + 1) & 1) * (BB * HH);  // h_t

        float acc = bias;

        // x-projection (K=256): plain cached loads (x is read-only input)
        {
            const float4* xr = (const float4*)(x + ((size_t)t * BB + (b0 + bl)) * II);
            const float4* wr = (const float4*)&WxL[c * WX_STRIDE];
            #pragma unroll 8
            for (int i = 0; i < II / 4; ++i) {
                float4 a = xr[i];
                float4 w = wr[i];
                acc = fmaf(a.x, w.x, acc);
                acc = fmaf(a.y, w.y, acc);
                acc = fmaf(a.z, w.z, acc);
                acc = fmaf(a.w, w.w, acc);
            }
        }
        // recurrent projection (K=512): h_{t-1} via L3-coherent (agent-scope) loads.
        // 8B relaxed-agent atomic loads -> global_load_dwordx2 sc0 sc1 (bypass L1+L2);
        // no cache maintenance needed anywhere.
        {
            const unsigned long long* hr =
                (const unsigned long long*)(hprev + (size_t)(b0 + bl) * HH);
            const float* wr = &WhL[c * WH_STRIDE];
            #pragma unroll 8
            for (int j = 0; j < HH / 2; ++j) {
                unsigned long long u =
                    __hip_atomic_load(hr + j, __ATOMIC_RELAXED, __HIP_MEMORY_SCOPE_AGENT);
                float2 w = *(const float2*)&wr[2 * j];
                acc = fmaf(__uint_as_float((unsigned)u),         w.x, acc);
                acc = fmaf(__uint_as_float((unsigned)(u >> 32)), w.y, acc);
            }
        }
        preL[bl * NCOLS + c] = acc;
        __syncthreads();

        // Gate combine: 128 threads own one (b,h) each; c lives in-register.
        if (tid < BTILE * HTILE) {
            const int b2 = tid >> 2;
            const int h2 = tid & 3;
            const float* p = &preL[b2 * NCOLS];
            float fg  = sigmoidf_(p[0 * HTILE + h2]);
            float ig  = sigmoidf_(p[1 * HTILE + h2]);
            float og  = sigmoidf_(p[2 * HTILE + h2]);
            float cg_ = tanhf(p[3 * HTILE + h2]);
            float cn = fg * c_state + ig * cg_;
            float hv = og * tanhf(cn);
            c_state = cn;

            // h_seq output: plain store (flushed at kernel end; only harness reads it)
            out[((size_t)t * BB + (b0 + b2)) * HH + hbase + h2] = hv;
            // h_t for other blocks: L3-coherent write-through store
            __hip_atomic_store(&hnext[(size_t)(b0 + b2) * HH + hbase + h2], hv,
                               __ATOMIC_RELAXED, __HIP_MEMORY_SCOPE_AGENT);
            if (t == TT - 1) {
                size_t r = (size_t)(b0 + b2) * HH + hbase + h2;
                out[HSEQ + r] = hv;                       // h_last
                out[HSEQ + (size_t)BB * HH + r] = cn;     // c_last
            }
        }

        // Drain own stores to the coherence point (vmcnt retire for sc1 stores = at L3),
        // then block-barrier so tid0's arrive is ordered after waves 0-1's h stores.
        asm volatile("s_waitcnt vmcnt(0)" ::: "memory");
        __syncthreads();

        // Lightweight device barrier: per-step counter, relaxed agent atomics,
        // NO fences / cache maintenance. Skipped after the last step.
        if (t != TT - 1) {
            if (tid == 0) {
                __hip_atomic_fetch_add(&cnt[t], 1u,
                                       __ATOMIC_RELAXED, __HIP_MEMORY_SCOPE_AGENT);
                while (__hip_atomic_load(&cnt[t], __ATOMIC_RELAXED,
                                         __HIP_MEMORY_SCOPE_AGENT) < (unsigned)NBLOCKS) {
                    __builtin_amdgcn_s_sleep(2);
                }
            }
            __syncthreads();
        }
    }
}

extern "C" void kernel_launch(void* const* d_in, const int* in_sizes, int n_in,
                              void* d_out, int out_size, void* d_ws, size_t ws_size,
                              hipStream_t stream)
{
    const float* x  = (const float*)d_in[0];
    const float* Wx = (const float*)d_in[1];
    const float* bx = (const float*)d_in[2];
    const float* Wh = (const float*)d_in[3];
    const float* bh = (const float*)d_in[4];
    float* out = (float*)d_out;

    // Workspace layout: [0,2KB) barrier counters; [2KB, 2KB+256KB) h ping-pong.
    unsigned int* cnt = (unsigned int*)d_ws;
    float* hbuf = (float*)((char*)d_ws + 2048);

    void* args[] = { (void*)&x, (void*)&Wx, (void*)&bx, (void*)&Wh, (void*)&bh,
                     (void*)&out, (void*)&cnt, (void*)&hbuf };
    hipLaunchCooperativeKernel((const void*)lstm_persistent,
                               dim3(NBLOCKS), dim3(NTHREADS),
                               args, 0, stream);
}

// Round 3
// 4491.268 us; speedup vs baseline: 8.9031x; 2.6460x over previous
//
#include <hip/hip_runtime.h>
#include <hip/hip_cooperative_groups.h>
#include <math.h>

namespace cg = cooperative_groups;

// Problem: SEQ_LEN=512, BATCH=64, INPUT=256, HIDDEN=512. fp32 in/out.
#define TT 512
#define BB 64
#define II 256
#define HH 512
#define KK 768              // concat K = II + HH

#define NTHREADS 256        // 4 waves
#define NBLOCKS  512        // 4 batch-tiles x 128 h-quad tiles; 2 blocks/CU
#define GRPSZ    128        // blocks per batch-tile group (barrier group)

// A/B LDS rows: K-major f16, padded 768+8 -> bank phase = minimal for b128 reads
#define KPAD 776

typedef _Float16 f16x8 __attribute__((ext_vector_type(8)));
typedef _Float16 f16x4 __attribute__((ext_vector_type(4)));
typedef float    f32x4 __attribute__((ext_vector_type(4)));

__device__ __forceinline__ float sig_(float v)  { return 1.0f / (1.0f + __expf(-v)); }
__device__ __forceinline__ float tanh_(float v) { float e = __expf(2.0f * v); return 1.0f - 2.0f / (e + 1.0f); }

__global__ void __launch_bounds__(NTHREADS, 2)
lstm_mfma(const float* __restrict__ x,
          const float* __restrict__ Wx,
          const float* __restrict__ bx,
          const float* __restrict__ Wh,
          const float* __restrict__ bh,
          float* __restrict__ out,
          unsigned int* __restrict__ cnt,          // [TT][4] padded x16 u32 (64B each)
          unsigned int* __restrict__ hbuf)         // [2][BB*HH/2] packed f16 pairs
{
    // LDS: A tile (16 x 776 f16), B tile (16 x 776 f16), reduce scratch, bias, h-out
    __shared__ _Float16 AL[16 * KPAD];             // 24,832 B
    __shared__ _Float16 BL[16 * KPAD];             // 24,832 B
    __shared__ float    redL[4 * 16 * 17];         //  4,352 B
    __shared__ float    biasL[16];
    __shared__ unsigned short houtL[64];

    cg::grid_group grid = cg::this_grid();

    const int blk = blockIdx.x;
    const int grp = blk & 3;            // batch-tile group
    const int b0  = grp * 16;           // 16 batch rows
    const int ct  = blk >> 2;           // h-quad tile: h units ct*4 .. ct*4+3
    const int tid = threadIdx.x;

    // ---- One-time: repack B = [Wx | Wh] cols into LDS, k-major f16 ----
    // col n (0..15): gate g = n>>2, h unit hc = ct*4 + (n&3); BL[n][k] = W(col)[k]
    for (int ch = tid; ch < 16 * 192; ch += NTHREADS) {
        int n = ch / 192, r = ch - n * 192;         // r: float4 chunk along K
        int g = n >> 2, hc = ct * 4 + (n & 3);
        float4 v = (r < 64)
            ? ((const float4*)(Wx + ((size_t)g * HH + hc) * II))[r]
            : ((const float4*)(Wh + ((size_t)g * HH + hc) * HH))[r - 64];
        f16x4 p = { (_Float16)v.x, (_Float16)v.y, (_Float16)v.z, (_Float16)v.w };
        *(f16x4*)&BL[n * KPAD + r * 4] = p;
    }
    if (tid < 16) {
        int g = tid >> 2, hc = ct * 4 + (tid & 3);
        biasL[tid] = bx[g * HH + hc] + bh[g * HH + hc];
    }

    // ---- One-time: zero barrier counters + h_{-1}, agent-visible ----
    {
        int gtid = blk * NTHREADS + tid;
        if (gtid < TT * 4 * 16)
            __hip_atomic_store(&cnt[gtid], 0u, __ATOMIC_RELAXED, __HIP_MEMORY_SCOPE_AGENT);
        int hz = gtid - TT * 4 * 16;
        if (hz >= 0 && hz < BB * HH / 2)
            __hip_atomic_store(&hbuf[hz], 0u, __ATOMIC_RELAXED, __HIP_MEMORY_SCOPE_AGENT);
    }
    grid.sync();   // only full-grid sync; publishes zeros + orders repack

    const size_t HSEQ = (size_t)TT * BB * HH;
    const int wv = tid >> 6;            // wave 0..3 (K-split: 192 each)
    const int L  = tid & 63;
    const int mA = L & 15;              // A row / C col index (lane&15)
    const int qd = L >> 4;              // lane quad

    float c_state = 0.0f;               // live in tid<64 threads

    for (int t = 0; t < TT; ++t) {
        const unsigned int* hsrc = hbuf + (size_t)(t & 1) * (BB * HH / 2);
        unsigned int*       hdst = hbuf + (size_t)((t + 1) & 1) * (BB * HH / 2);

        // ---- Stage A = [x_t | h_{t-1}] rows b0..b0+15 into LDS (f16) ----
        // x part: 16 rows x 64 float4 (L1/L2-cached, read-only input)
        for (int ch = tid; ch < 1024; ch += NTHREADS) {
            int row = ch >> 6, pos = ch & 63;
            float4 v = ((const float4*)(x + ((size_t)t * BB + b0 + row) * II))[pos];
            f16x4 p = { (_Float16)v.x, (_Float16)v.y, (_Float16)v.z, (_Float16)v.w };
            *(f16x4*)&AL[row * KPAD + pos * 4] = p;
        }
        // h part: 16 rows x 128 8B chunks, L3-coherent loads (bypass L1/L2)
        for (int ch = tid; ch < 2048; ch += NTHREADS) {
            int row = ch >> 7, pos = ch & 127;
            unsigned long long u = __hip_atomic_load(
                (const unsigned long long*)hsrc + (size_t)(b0 + row) * 128 + pos,
                __ATOMIC_RELAXED, __HIP_MEMORY_SCOPE_AGENT);
            *(unsigned long long*)((char*)AL + row * (KPAD * 2) + II * 2 + pos * 8) = u;
        }
        __syncthreads();

        // ---- MFMA: wave wv covers k in [wv*192, wv*192+192), 6 x K=32 ----
        {
            const char* Ab = (const char*)AL + mA * (KPAD * 2) + qd * 16;
            const char* Bb = (const char*)BL + mA * (KPAD * 2) + qd * 16;
            const int kb = wv * 192;
            f32x4 acc = { 0.f, 0.f, 0.f, 0.f };
            #pragma unroll
            for (int u = 0; u < 6; ++u) {
                f16x8 a = *(const f16x8*)(Ab + (kb + u * 32) * 2);
                f16x8 b = *(const f16x8*)(Bb + (kb + u * 32) * 2);
                acc = __builtin_amdgcn_mfma_f32_16x16x32_f16(a, b, acc, 0, 0, 0);
            }
            // C layout: lane holds D[row=qd*4+r][col=L&15]
            #pragma unroll
            for (int r = 0; r < 4; ++r)
                redL[(wv * 16 + qd * 4 + r) * 17 + mA] = acc[r];
        }
        __syncthreads();

        // ---- Epilogue: 64 threads own (b, hj); reduce 4 K-partials + gates ----
        if (tid < 64) {
            const int b  = tid >> 2;
            const int hj = tid & 3;
            float pre[4];
            #pragma unroll
            for (int g = 0; g < 4; ++g) {
                int n = g * 4 + hj;
                float s = biasL[n];
                #pragma unroll
                for (int w = 0; w < 4; ++w) s += redL[(w * 16 + b) * 17 + n];
                pre[g] = s;
            }
            float fg = sig_(pre[0]);
            float ig = sig_(pre[1]);
            float og = sig_(pre[2]);
            float cn = fg * c_state + ig * tanh_(pre[3]);
            float hv = og * tanh_(cn);
            c_state = cn;

            out[((size_t)t * BB + b0 + b) * HH + ct * 4 + hj] = hv;
            _Float16 hh = (_Float16)hv;
            houtL[tid] = *(unsigned short*)&hh;
            if (t == TT - 1) {
                size_t r = (size_t)(b0 + b) * HH + ct * 4 + hj;
                out[HSEQ + r] = hv;                       // h_last
                out[HSEQ + (size_t)BB * HH + r] = cn;     // c_last
            }
        }
        __syncthreads();

        // ---- Publish h_t (packed f16 pairs), L3-coherent ----
        if (tid < 32) {
            int b = tid >> 1, jj = tid & 1;
            unsigned int v = (unsigned int)houtL[b * 4 + jj * 2]
                           | ((unsigned int)houtL[b * 4 + jj * 2 + 1] << 16);
            __hip_atomic_store(&hdst[(size_t)(b0 + b) * 256 + ct * 2 + jj], v,
                               __ATOMIC_RELAXED, __HIP_MEMORY_SCOPE_AGENT);
        }
        asm volatile("s_waitcnt vmcnt(0)" ::: "memory");
        __syncthreads();

        // ---- Group-local barrier: 128 blocks sharing this batch-tile ----
        if (t != TT - 1) {
            if (tid == 0) {
                unsigned int* c = &cnt[(t * 4 + grp) * 16];   // 64B-padded counter
                __hip_atomic_fetch_add(c, 1u, __ATOMIC_RELAXED, __HIP_MEMORY_SCOPE_AGENT);
                while (__hip_atomic_load(c, __ATOMIC_RELAXED,
                                         __HIP_MEMORY_SCOPE_AGENT) < (unsigned)GRPSZ) {
                    __builtin_amdgcn_s_sleep(1);
                }
            }
            __syncthreads();
        }
    }
}

extern "C" void kernel_launch(void* const* d_in, const int* in_sizes, int n_in,
                              void* d_out, int out_size, void* d_ws, size_t ws_size,
                              hipStream_t stream)
{
    const float* x  = (const float*)d_in[0];
    const float* Wx = (const float*)d_in[1];
    const float* bx = (const float*)d_in[2];
    const float* Wh = (const float*)d_in[3];
    const float* bh = (const float*)d_in[4];
    float* out = (float*)d_out;

    // ws layout: [0,128KB) barrier counters (512*4 x 64B); [128KB,256KB) h f16 ping-pong
    unsigned int* cnt  = (unsigned int*)d_ws;
    unsigned int* hbuf = (unsigned int*)((char*)d_ws + TT * 4 * 64);

    void* args[] = { (void*)&x, (void*)&Wx, (void*)&bx, (void*)&Wh, (void*)&bh,
                     (void*)&out, (void*)&cnt, (void*)&hbuf };
    hipLaunchCooperativeKernel((const void*)lstm_mfma,
                               dim3(NBLOCKS), dim3(NTHREADS),
                               args, 0, stream);
}

// Round 4
// 1668.528 us; speedup vs baseline: 23.9650x; 2.6918x over previous
//
#include <hip/hip_runtime.h>
#include <hip/hip_cooperative_groups.h>
#include <math.h>

namespace cg = cooperative_groups;

// Problem: SEQ_LEN=512, BATCH=64, INPUT=256, HIDDEN=512. fp32 in/out.
#define TT 512
#define BB 64
#define II 256
#define HH 512

#define NTHREADS 512        // 8 waves
#define NGRP 4              // batch groups (16 rows each)
#define NCT  16             // h-tile blocks per group (32 h-units each)
#define NBLOCKS (NGRP*NCT)  // 64 blocks total

#define KPAD 776            // f16 elements per A row (768 + 8 pad)

typedef _Float16 f16x8 __attribute__((ext_vector_type(8)));
typedef _Float16 f16x4 __attribute__((ext_vector_type(4)));
typedef float    f32x4 __attribute__((ext_vector_type(4)));

__device__ __forceinline__ float sig_(float v)  { return 1.0f / (1.0f + __expf(-v)); }
__device__ __forceinline__ float tanh_(float v) { float e = __expf(2.0f * v); return 1.0f - 2.0f / (e + 1.0f); }

__global__ void __launch_bounds__(NTHREADS, 2)
lstm_mfma2(const float* __restrict__ x,
           const float* __restrict__ Wx,
           const float* __restrict__ bx,
           const float* __restrict__ Wh,
           const float* __restrict__ bh,
           float* __restrict__ out,
           unsigned int* __restrict__ flags,   // [NGRP][64] u32 (256B per group)
           unsigned int* __restrict__ hbuf)    // [2][BB][256] u32 = packed f16 pairs
{
    __shared__ _Float16 AL[16 * KPAD];     // A = [x_t | h_{t-1}] tile, 24,832 B
    __shared__ float    exch[8 * 16 * 20]; // per-wave gate exchange, 10,240 B

    cg::grid_group grid = cg::this_grid();

    const int blk  = blockIdx.x;
    const int grp  = blk & 3;          // batch group (16 rows)
    const int b0   = grp * 16;
    const int ct   = blk >> 2;         // 0..15, h-units [ct*32, ct*32+32)
    const int hblk = ct * 32;

    const int tid = threadIdx.x;
    const int wv  = tid >> 6;          // wave 0..7: h-quad hblk + wv*4
    const int L   = tid & 63;
    const int n   = L & 15;            // MFMA A-row m / B-col n (lane&15)
    const int qd  = L >> 4;            // lane quad -> k = qd*8..qd*8+7

    // ---- Preload B fragments into registers; constant across ALL 512 steps ----
    // B col n of wave wv: gate g = n&3, h-unit hu = hblk + wv*4 + (n>>2)
    const int g  = n & 3;
    const int hu = hblk + wv * 4 + (n >> 2);
    f16x8 bfr[24];
    #pragma unroll
    for (int kc = 0; kc < 24; ++kc) {
        int k0 = kc * 32 + qd * 8;     // kc<8 entirely in x-part, kc>=8 in h-part
        const float* src = (kc < 8)
            ? (Wx + ((size_t)g * HH + hu) * II + k0)
            : (Wh + ((size_t)g * HH + hu) * HH + (k0 - 256));
        float4 u0 = ((const float4*)src)[0];
        float4 u1 = ((const float4*)src)[1];
        f16x8 b = { (_Float16)u0.x, (_Float16)u0.y, (_Float16)u0.z, (_Float16)u0.w,
                    (_Float16)u1.x, (_Float16)u1.y, (_Float16)u1.z, (_Float16)u1.w };
        bfr[kc] = b;
    }

    // Epilogue ownership: lane -> (batch be, h-unit he); c_state lives here forever
    const int be  = L >> 2;
    const int hle = L & 3;
    const int he  = hblk + wv * 4 + hle;
    float bias4[4];
    #pragma unroll
    for (int g2 = 0; g2 < 4; ++g2) bias4[g2] = bx[g2 * HH + he] + bh[g2 * HH + he];

    // ---- Zero own flag, then the single full-grid sync ----
    if (tid == 0)
        __hip_atomic_store(&flags[grp * 64 + ct], 0u,
                           __ATOMIC_RELAXED, __HIP_MEMORY_SCOPE_AGENT);
    grid.sync();

    const size_t HSEQ = (size_t)TT * BB * HH;
    float c_state = 0.0f;
    float* exchW = &exch[wv * 16 * 20];

    for (int t = 0; t < TT; ++t) {
        // ---- Stage x_t (no dependence on h: happens before/while polling) ----
        #pragma unroll
        for (int i = 0; i < 2; ++i) {
            int ch = tid + i * NTHREADS;           // 0..1023
            int row = ch >> 6, pos = ch & 63;
            float4 v = ((const float4*)(x + ((size_t)t * BB + b0 + row) * II))[pos];
            f16x4 p = { (_Float16)v.x, (_Float16)v.y, (_Float16)v.z, (_Float16)v.w };
            *(f16x4*)&AL[row * KPAD + pos * 4] = p;
        }

        // ---- Wave 0 polls the 16 group flags (independent producer stores) ----
        if (t > 0 && wv == 0) {
            const unsigned int* fp = flags + grp * 64;
            for (;;) {
                unsigned f = (L < NCT)
                    ? __hip_atomic_load(&fp[L], __ATOMIC_RELAXED, __HIP_MEMORY_SCOPE_AGENT)
                    : 0xFFFFFFFFu;
                if (__all((int)(f >= (unsigned)t))) break;
                __builtin_amdgcn_s_sleep(1);
            }
        }
        __syncthreads();   // x staged + h_{t-1} known visible at L3

        // ---- Stage h_{t-1} rows b0..b0+15 (L3-coherent, 4 x 8B per thread) ----
        if (t > 0) {
            const unsigned long long* hsrc =
                (const unsigned long long*)(hbuf + (size_t)(t & 1) * (BB * 256));
            #pragma unroll
            for (int i = 0; i < 4; ++i) {
                int ch = tid + i * NTHREADS;       // 0..2047
                int row = ch >> 7, pos = ch & 127;
                unsigned long long u = __hip_atomic_load(
                    hsrc + (size_t)(b0 + row) * 128 + pos,
                    __ATOMIC_RELAXED, __HIP_MEMORY_SCOPE_AGENT);
                *(unsigned long long*)((char*)AL + row * (KPAD * 2) + II * 2 + pos * 8) = u;
            }
            __syncthreads();
        }

        // ---- MFMA: full K=768 per wave, B from registers, no K-split ----
        const char* Ab = (const char*)AL + n * (KPAD * 2) + qd * 16;
        f32x4 acc = { 0.f, 0.f, 0.f, 0.f };
        #pragma unroll
        for (int kc = 0; kc < 8; ++kc) {           // x-part
            f16x8 a = *(const f16x8*)(Ab + kc * 64);
            acc = __builtin_amdgcn_mfma_f32_16x16x32_f16(a, bfr[kc], acc, 0, 0, 0);
        }
        if (t > 0) {
            #pragma unroll
            for (int kc = 8; kc < 24; ++kc) {      // h-part
                f16x8 a = *(const f16x8*)(Ab + kc * 64);
                acc = __builtin_amdgcn_mfma_f32_16x16x32_f16(a, bfr[kc], acc, 0, 0, 0);
            }
        }

        // ---- Intra-wave exchange: C[row=qd*4+r][col=n] -> gates per (b,h) ----
        #pragma unroll
        for (int r = 0; r < 4; ++r)
            exchW[(qd * 4 + r) * 20 + n] = acc[r];
        // same wave writes then reads: lockstep, no barrier needed
        float4 pre4 = *(const float4*)&exchW[be * 20 + hle * 4];

        // ---- Gates; c_state in-register ----
        float pf = pre4.x + bias4[0];
        float pi = pre4.y + bias4[1];
        float po = pre4.z + bias4[2];
        float pc = pre4.w + bias4[3];
        float fg = sig_(pf), ig = sig_(pi), og = sig_(po);
        float cn = fg * c_state + ig * tanh_(pc);
        float hv = og * tanh_(cn);
        c_state = cn;

        out[((size_t)t * BB + b0 + be) * HH + he] = hv;
        if (t == TT - 1) {
            size_t r = (size_t)(b0 + be) * HH + he;
            out[HSEQ + r] = hv;                        // h_last
            out[HSEQ + (size_t)BB * HH + r] = cn;      // c_last
        }

        // ---- Publish h_t as packed f16 pairs (L3-coherent) ----
        {
            union { _Float16 f; unsigned short u; } cv; cv.f = (_Float16)hv;
            unsigned mine  = cv.u;
            unsigned other = (unsigned)__shfl_xor((int)mine, 1, 64);
            if ((hle & 1) == 0) {
                unsigned pk = mine | (other << 16);
                unsigned int* hdst = hbuf + (size_t)((t + 1) & 1) * (BB * 256);
                __hip_atomic_store(&hdst[(unsigned)(b0 + be) * 256 + (unsigned)(he >> 1)],
                                   pk, __ATOMIC_RELAXED, __HIP_MEMORY_SCOPE_AGENT);
            }
        }

        // syncthreads drains vmcnt (all waves' h stores at L3) before the flag
        __syncthreads();
        if (t != TT - 1 && tid == 0)
            __hip_atomic_store(&flags[grp * 64 + ct], (unsigned)(t + 1),
                               __ATOMIC_RELAXED, __HIP_MEMORY_SCOPE_AGENT);
    }
}

extern "C" void kernel_launch(void* const* d_in, const int* in_sizes, int n_in,
                              void* d_out, int out_size, void* d_ws, size_t ws_size,
                              hipStream_t stream)
{
    const float* x  = (const float*)d_in[0];
    const float* Wx = (const float*)d_in[1];
    const float* bx = (const float*)d_in[2];
    const float* Wh = (const float*)d_in[3];
    const float* bh = (const float*)d_in[4];
    float* out = (float*)d_out;

    // ws: [0,4KB) epoch flags; [4KB, 4KB+128KB) h f16-pair ping-pong
    unsigned int* flags = (unsigned int*)d_ws;
    unsigned int* hbuf  = (unsigned int*)((char*)d_ws + 4096);

    void* args[] = { (void*)&x, (void*)&Wx, (void*)&bx, (void*)&Wh, (void*)&bh,
                     (void*)&out, (void*)&flags, (void*)&hbuf };
    hipLaunchCooperativeKernel((const void*)lstm_mfma2,
                               dim3(NBLOCKS), dim3(NTHREADS),
                               args, 0, stream);
}